// Round 3
// baseline (3394.263 us; speedup 1.0000x reference)
//
#include <hip/hip_runtime.h>

// Problem constants (match reference setup_inputs)
constexpr int L = 64;
constexpr int P = 32768;
constexpr int N = L * P;          // 2,097,152 nodes
constexpr int E_PER = 262144;     // edges per non-source level
constexpr int NLEVELS = L - 1;    // 63 edge levels

constexpr int NBLOCKS = 512;      // 2 blocks/CU on 256 CUs (cooperative-guaranteed)
constexpr int NTHREADS = 256;
constexpr int EDGES_PER_THREAD = E_PER / (NBLOCKS * NTHREADS);  // = 2

// ---- agent-scope (device-coherent, LLC-backed) memory ops -------------------
// Per-XCD L2s are NOT coherent. All accesses to `out` use agent scope so the
// data lives coherently at the memory-side Infinity Cache; per-XCD L2 never
// holds stale/dirty copies. Edge arrays are read-only -> normal cached loads.
__device__ __forceinline__ float agent_load_f(const float* p) {
    return __hip_atomic_load(p, __ATOMIC_RELAXED, __HIP_MEMORY_SCOPE_AGENT);
}
__device__ __forceinline__ void agent_store_f(float* p, float v) {
    __hip_atomic_store(p, v, __ATOMIC_RELAXED, __HIP_MEMORY_SCOPE_AGENT);
}

// ---- hand-rolled grid barrier ----------------------------------------------
// Arrival: block b's thread 0 release-stores flags[b] = lvl (no contention).
// Detection: block 0's threads poll flags in parallel (2 flags/thread).
// Release: block 0 thread 0 release-stores *gen = lvl; all others spin on it.
// flags/gen live in d_ws: poison 0xAA... is negative as signed int, so
// "< lvl" (lvl >= 1) spins safely until a real store lands. Monotonic, no reset.
__device__ __forceinline__ void grid_barrier(int lvl, int* flags, int* gen) {
    __syncthreads();   // all threads' atomics drained (vmcnt(0)) before arrive
    if (blockIdx.x == 0) {
        for (int b = threadIdx.x; b < NBLOCKS; b += NTHREADS) {
            if (b == 0) continue;
            while (__hip_atomic_load(&flags[b], __ATOMIC_ACQUIRE,
                                     __HIP_MEMORY_SCOPE_AGENT) < lvl)
                __builtin_amdgcn_s_sleep(1);
        }
        __syncthreads();
        if (threadIdx.x == 0)
            __hip_atomic_store(gen, lvl, __ATOMIC_RELEASE,
                               __HIP_MEMORY_SCOPE_AGENT);
        __syncthreads();
    } else {
        if (threadIdx.x == 0) {
            __hip_atomic_store(&flags[blockIdx.x], lvl, __ATOMIC_RELEASE,
                               __HIP_MEMORY_SCOPE_AGENT);
            while (__hip_atomic_load(gen, __ATOMIC_ACQUIRE,
                                     __HIP_MEMORY_SCOPE_AGENT) < lvl)
                __builtin_amdgcn_s_sleep(1);
        }
        __syncthreads();
    }
}

__global__ void __launch_bounds__(NTHREADS)
pathfinder_kernel(const float* __restrict__ hdr,
                  const int* __restrict__ src,
                  const int* __restrict__ dst,
                  float* __restrict__ out,
                  int* __restrict__ flags,   // [NBLOCKS] in d_ws
                  int* __restrict__ gen) {   // [1] in d_ws
    const int tid = blockIdx.x * NTHREADS + threadIdx.x;   // 0..131071

    // ---- init: out = hdr via agent stores (keeps L2 clean of `out` lines) ----
    for (int i = tid; i < N; i += NBLOCKS * NTHREADS)
        agent_store_f(&out[i], hdr[i]);
    grid_barrier(1, flags, gen);

    // ---- 63 sequential levels ----
    for (int l = 0; l < NLEVELS; ++l) {
        const int2* __restrict__ s2 = (const int2*)(src + (size_t)l * E_PER);
        const int2* __restrict__ d2 = (const int2*)(dst + (size_t)l * E_PER);
        const int2 s = s2[tid];
        const int2 d = d2[tid];
        // issue both gathers before uses (MLP)
        const float va = agent_load_f(&out[s.x]);
        const float vb = agent_load_f(&out[s.y]);
        // values are all >= 0 -> uint-bitpattern atomicMax == float max.
        // atomicMax on global is agent scope (executes at LLC, cross-XCD).
        atomicMax((unsigned int*)out + d.x, __float_as_uint(va + 1.0f));
        atomicMax((unsigned int*)out + d.y, __float_as_uint(vb + 1.0f));

        if (l < NLEVELS - 1)
            grid_barrier(l + 2, flags, gen);
        // after the last level: kernel end handles final visibility
    }
}

extern "C" void kernel_launch(void* const* d_in, const int* in_sizes, int n_in,
                              void* d_out, int out_size, void* d_ws, size_t ws_size,
                              hipStream_t stream) {
    const float* hdr = (const float*)d_in[0];
    const int*   src = (const int*)d_in[1];
    const int*   dst = (const int*)d_in[2];
    float*       out = (float*)d_out;
    int*         flags = (int*)d_ws;          // NBLOCKS ints
    int*         gen   = flags + NBLOCKS;     // 1 int (own region)

    void* args[] = {(void*)&hdr, (void*)&src, (void*)&dst,
                    (void*)&out, (void*)&flags, (void*)&gen};
    // cooperative launch guarantees all 512 blocks co-resident (2/CU)
    hipLaunchCooperativeKernel((void*)pathfinder_kernel,
                               dim3(NBLOCKS), dim3(NTHREADS), args, 0, stream);
}

// Round 4
// 2808.197 us; speedup vs baseline: 1.2087x; 1.2087x over previous
//
#include <hip/hip_runtime.h>

// Problem constants (match reference setup_inputs)
constexpr int L = 64;
constexpr int P = 32768;
constexpr int N = L * P;          // 2,097,152 nodes
constexpr int E_PER = 262144;     // edges per non-source level
constexpr int NLEVELS = L - 1;    // 63 edge levels

constexpr int NBLOCKS = 1024;     // 4 blocks/CU on 256 CUs (cooperative co-resident)
constexpr int NTHREADS = 256;     // 262144 threads = exactly 1 edge/thread/level

// ---- relaxed agent-scope flag ops (LLC-direct, NO per-op cache invalidate) --
__device__ __forceinline__ int agent_ld(const int* p) {
    return __hip_atomic_load(p, __ATOMIC_RELAXED, __HIP_MEMORY_SCOPE_AGENT);
}
__device__ __forceinline__ void agent_st(int* p, int v) {
    __hip_atomic_store(p, v, __ATOMIC_RELAXED, __HIP_MEMORY_SCOPE_AGENT);
}

// ---- hand-rolled grid barrier, cheap version ------------------------------
// Visibility protocol:
//  * level-l atomics are sc1 write-through; __syncthreads() drains vmcnt(0)
//    per wave -> all acked at the memory-side LLC -> device-visible.
//  * flag/gen traffic is RELAXED sc1 (no invalidate per poll).
//  * ONE acquire fence at agent scope on exit emits buffer_inv (L1+L2
//    invalidate) so the next level's NORMAL cached loads re-fetch LLC-fresh
//    data. Register-held values (prefetched edge indices) are unaffected.
// flags/gen live in d_ws: 0xAA poison is negative as int -> "< lvl" spins
// safely until a real store. Monotonic generations 1..64, no reset needed.
__device__ __forceinline__ void grid_barrier(int lvl, int* flags, int* gen) {
    __syncthreads();   // drains all waves' vmem (atomics acked at LLC)
    if (blockIdx.x == 0) {
        for (int b = threadIdx.x; b < NBLOCKS; b += NTHREADS) {
            if (b != 0) {
                while (agent_ld(&flags[b]) < lvl) __builtin_amdgcn_s_sleep(1);
            }
        }
        __syncthreads();                  // all flags verified collectively
        if (threadIdx.x == 0) agent_st(gen, lvl);
    } else {
        if (threadIdx.x == 0) {
            agent_st(&flags[blockIdx.x], lvl);
            while (agent_ld(gen) < lvl) __builtin_amdgcn_s_sleep(1);
        }
        __syncthreads();
    }
    __builtin_amdgcn_fence(__ATOMIC_ACQUIRE, "agent");   // inv L1+L2 once/level
}

__global__ void __launch_bounds__(NTHREADS)
pathfinder_kernel(const float* __restrict__ hdr,
                  const int* __restrict__ src,
                  const int* __restrict__ dst,
                  float* __restrict__ out,
                  int* __restrict__ flags,   // [NBLOCKS] in d_ws
                  int* __restrict__ gen) {   // [1] in d_ws (own cache line)
    const int tid = blockIdx.x * NTHREADS + threadIdx.x;   // 0..262143

    // ---- init: out = hdr, vectorized normal stores (float4 x2 per thread) --
    {
        const float4* h4 = (const float4*)hdr;
        float4* o4 = (float4*)out;
        o4[tid]            = h4[tid];               // N/4 = 524288 = 2*262144
        o4[tid + E_PER]    = h4[tid + E_PER];
    }
    // flush dirty init lines from per-XCD L2 to LLC before anyone gathers
    __builtin_amdgcn_fence(__ATOMIC_RELEASE, "agent");   // buffer_wbl2
    grid_barrier(1, flags, gen);

    // ---- 63 sequential levels, 1 edge/thread ----
    // Edge indices for level l+1 are prefetched into REGISTERS before the
    // barrier (edge arrays are immutable; registers survive the cache inv),
    // overlapping the index-load latency with barrier spin time.
    int si = src[tid];
    int di = dst[tid];
    for (int l = 0; l < NLEVELS; ++l) {
        int si_n = 0, di_n = 0;
        if (l + 1 < NLEVELS) {
            si_n = src[(size_t)(l + 1) * E_PER + tid];
            di_n = dst[(size_t)(l + 1) * E_PER + tid];
        }
        // gather: NORMAL cached load (L1/L2) -- within a level the gathered
        // range [0,(l+1)P) is disjoint from the written range, and the
        // per-level acquire fence handles cross-level freshness.
        const float v = out[si] + 1.0f;
        // all h >= 0 -> uint-bitpattern atomicMax == float max; sc1
        // write-through executes at the memory-side LLC (cross-XCD correct).
        atomicMax((unsigned int*)out + di, __float_as_uint(v));

        if (l < NLEVELS - 1) grid_barrier(l + 2, flags, gen);
        si = si_n; di = di_n;
    }
}

extern "C" void kernel_launch(void* const* d_in, const int* in_sizes, int n_in,
                              void* d_out, int out_size, void* d_ws, size_t ws_size,
                              hipStream_t stream) {
    const float* hdr = (const float*)d_in[0];
    const int*   src = (const int*)d_in[1];
    const int*   dst = (const int*)d_in[2];
    float*       out = (float*)d_out;
    int*         flags = (int*)d_ws;               // NBLOCKS ints (4 KB)
    int*         gen   = flags + NBLOCKS + 16;     // own cache line

    void* args[] = {(void*)&hdr, (void*)&src, (void*)&dst,
                    (void*)&out, (void*)&flags, (void*)&gen};
    // cooperative launch guarantees all 1024 blocks co-resident (4/CU)
    hipLaunchCooperativeKernel((void*)pathfinder_kernel,
                               dim3(NBLOCKS), dim3(NTHREADS), args, 0, stream);
}